// Round 3
// baseline (352.227 us; speedup 1.0000x reference)
//
#include <hip/hip_runtime.h>
#include <stdint.h>

#define D_MODEL 1024
#define NHEAD 16
#define HEAD_DIM 64
#define BATCH 4
#define SEQ 2048
#define ROWS (BATCH*SEQ)   // 8192

typedef __attribute__((ext_vector_type(8))) short short8;
typedef __attribute__((ext_vector_type(4))) float f32x4;
typedef __attribute__((ext_vector_type(2))) unsigned int u32x2;
typedef unsigned short u16;
typedef unsigned int u32;

// log2(e)/8 folded into Q at projection time
#define QSCALE 0.18033688011112042f

// fp32 -> bf16 round-to-nearest-even
__device__ __forceinline__ u16 f2b(float f) {
  union { float f; uint32_t u; } in; in.f = f;
  uint32_t u = in.u;
  return (u16)((u + 0x7FFFu + ((u >> 16) & 1u)) >> 16);
}

// async global->LDS, 16B/lane; HW dest = wave-uniform base + lane*16
__device__ __forceinline__ void async_lds16(const void* g, void* l) {
  __builtin_amdgcn_global_load_lds(
      (const __attribute__((address_space(1))) uint32_t*)g,
      (__attribute__((address_space(3))) uint32_t*)l,
      16, 0, 0);
}

// pack two f32 into bf16x2 (round-half-up)
__device__ __forceinline__ u32 pack_bf16(float lo, float hi) {
  union { float f; uint32_t u; } a, b; a.f = lo; b.f = hi;
  return __builtin_amdgcn_perm(b.u + 0x8000u, a.u + 0x8000u, 0x07060302u);
}

// ---------------- fp32 -> bf16 bulk convert (x and y fused, z picks input) ----------------
__global__ void __launch_bounds__(256) cvt_kernel(const float* __restrict__ x,
                                                  const float* __restrict__ y,
                                                  u16* __restrict__ xb,
                                                  u16* __restrict__ yb) {
  const float* in = blockIdx.y ? y : x;
  u16* out = blockIdx.y ? yb : xb;
  int i = blockIdx.x * 256 + threadIdx.x;
  float4 v = ((const float4*)in)[i];
  ushort4 o;
  o.x = f2b(v.x); o.y = f2b(v.y); o.z = f2b(v.z); o.w = f2b(v.w);
  ((ushort4*)out)[i] = o;
}

// ---------------- weight transpose + convert (4 weights fused via z) ----------------
__global__ void __launch_bounds__(256) wtrans_kernel(const float* __restrict__ wq,
                                                     const float* __restrict__ wk,
                                                     const float* __restrict__ wv,
                                                     const float* __restrict__ wo,
                                                     u16* __restrict__ wtbase) {
  __shared__ u16 tile[64 * 65];
  int z = blockIdx.z;
  const float* w = (z == 0) ? wq : (z == 1 ? wk : (z == 2 ? wv : wo));
  u16* wt = wtbase + (size_t)z * D_MODEL * D_MODEL;
  int t = threadIdx.x;
  int c = t & 63, rb = t >> 6;
  int k0 = blockIdx.x * 64, n0 = blockIdx.y * 64;
#pragma unroll
  for (int i = 0; i < 16; ++i) {
    int r = rb + i * 4;
    tile[c * 65 + r] = f2b(w[(size_t)(k0 + r) * D_MODEL + n0 + c]);
  }
  __syncthreads();
#pragma unroll
  for (int i = 0; i < 16; ++i) {
    int r = rb + i * 4;
    wt[(size_t)(n0 + r) * D_MODEL + k0 + c] = tile[r * 65 + c];
  }
}

// ---------------- GEMM core: C[M][N] = A[M][K] * Bt[N][K]^T + bias ----------------
// MODE 0: bf16 row-major out, bias per col, scaled. MODE 1: f32 row-major out.
// MODE 2: V^T sigma-layout out (vt[(b*16+h)*64+d][sigma(s)]), bias per row.
template <int MODE>
__device__ __forceinline__ void gemm_bt_core(const u16* __restrict__ A,
                                             const u16* __restrict__ Bt,
                                             const float* __restrict__ bias,
                                             void* __restrict__ Cout, float scale,
                                             int m0, int n0) {
  constexpr int K = 1024, N = 1024;
  __shared__ u16 As[128 * 32];
  __shared__ u16 Bs[128 * 32];
  int tid = threadIdx.x;
  int wave = tid >> 6, lane = tid & 63;
  int quad = lane >> 4, l16 = lane & 15;
  int wm = wave & 1, wn = wave >> 1;

  f32x4 acc[4][4];
#pragma unroll
  for (int mi = 0; mi < 4; ++mi)
#pragma unroll
    for (int ni = 0; ni < 4; ++ni) acc[mi][ni] = f32x4{0.f, 0.f, 0.f, 0.f};

  int srow = lane >> 2;
  int scol = (lane & 3) * 16;

  for (int k0 = 0; k0 < K; k0 += 32) {
#pragma unroll
    for (int i = 0; i < 2; ++i) {
      int c = wave * 2 + i;
      const char* ga = (const char*)(A + (size_t)(m0 + c * 16 + srow) * K + k0) + scol;
      async_lds16(ga, (char*)As + c * 1024);
      const char* gb = (const char*)(Bt + (size_t)(n0 + c * 16 + srow) * K + k0) + scol;
      async_lds16(gb, (char*)Bs + c * 1024);
    }
    __syncthreads();

    short8 af[4], bf[4];
#pragma unroll
    for (int mi = 0; mi < 4; ++mi)
      af[mi] = *(const short8*)(As + (wm * 64 + mi * 16 + l16) * 32 + quad * 8);
#pragma unroll
    for (int ni = 0; ni < 4; ++ni)
      bf[ni] = *(const short8*)(Bs + (wn * 64 + ni * 16 + l16) * 32 + quad * 8);
#pragma unroll
    for (int mi = 0; mi < 4; ++mi)
#pragma unroll
      for (int ni = 0; ni < 4; ++ni)
        acc[mi][ni] = __builtin_amdgcn_mfma_f32_16x16x32_bf16(af[mi], bf[ni], acc[mi][ni], 0, 0, 0);
    __syncthreads();
  }

  if (MODE == 2) {
#pragma unroll
    for (int ni = 0; ni < 4; ++ni) {
      int col = n0 + wn * 64 + ni * 16 + l16;       // s_glob
      int bb = col >> 11, ss = col & 2047;
      size_t sbase = (size_t)(ss & ~63) + 4 * l16 + ni;  // sigma position
#pragma unroll
      for (int mi = 0; mi < 4; ++mi) {
        int row0 = m0 + wm * 64 + mi * 16 + quad * 4;
#pragma unroll
        for (int r = 0; r < 4; ++r) {
          int dcol = row0 + r;
          float vv = acc[mi][ni][r] + bias[dcol];
          int hh = dcol >> 6, dd = dcol & 63;
          size_t vtrow = ((size_t)bb * 16 + hh) * 64 + dd;
          ((u16*)Cout)[vtrow * 2048 + sbase] = f2b(vv);
        }
      }
    }
  } else {
#pragma unroll
    for (int ni = 0; ni < 4; ++ni) {
      int col = n0 + wn * 64 + ni * 16 + l16;
      float bv = bias[col];
#pragma unroll
      for (int mi = 0; mi < 4; ++mi) {
        int row = m0 + wm * 64 + mi * 16 + quad * 4;
#pragma unroll
        for (int r = 0; r < 4; ++r) {
          float vv = (acc[mi][ni][r] + bv) * scale;
          if (MODE == 1)
            ((float*)Cout)[(size_t)(row + r) * N + col] = vv;
          else
            ((u16*)Cout)[(size_t)(row + r) * N + col] = f2b(vv);
        }
      }
    }
  }
}

// QKV fused: grid (512, 3). z=0: Q=x*wq (scaled); z=1: K=y*wk; z=2: V^T = wvT * yb^T
__global__ void __launch_bounds__(256) gemm_qkv_kernel(
    const u16* __restrict__ xb, const u16* __restrict__ yb,
    const u16* __restrict__ wqT, const u16* __restrict__ wkT, const u16* __restrict__ wvT,
    const float* __restrict__ bq, const float* __restrict__ bk, const float* __restrict__ bv,
    u16* __restrict__ q, u16* __restrict__ k, u16* __restrict__ vt) {
  int bx = blockIdx.x, z = blockIdx.y;
  if (z == 0) {
    gemm_bt_core<0>(xb, wqT, bq, q, QSCALE, (bx >> 3) * 128, (bx & 7) * 128);
  } else if (z == 1) {
    gemm_bt_core<0>(yb, wkT, bk, k, 1.0f, (bx >> 3) * 128, (bx & 7) * 128);
  } else {
    gemm_bt_core<2>(wvT, yb, bv, vt, 1.0f, (bx & 7) * 128, (bx >> 3) * 128);
  }
}

__global__ void __launch_bounds__(256) gemm_o_kernel(const u16* __restrict__ ao,
                                                     const u16* __restrict__ woT,
                                                     const float* __restrict__ bo,
                                                     float* __restrict__ out) {
  gemm_bt_core<1>(ao, woT, bo, out, 1.0f, blockIdx.y * 128, blockIdx.x * 128);
}

// ---------------- flash attention, no-max softmax, dbuf single-barrier ----------------
// grid (B*H, SEQ/128): all q-blocks of one bh land on one XCD (L2 KV locality).
// Block 256 = 4 waves; wave owns 32 q-rows; kv-tile 64 keys, double-buffered.
// K-loop: [barrier drains tile t] -> issue tile t+1 into other buffer -> compute tile t.
__global__ void __launch_bounds__(256, 4) attn_kernel(const u16* __restrict__ Q,
                                                      const u16* __restrict__ Kp,
                                                      const u16* __restrict__ Vt,
                                                      u16* __restrict__ Outp) {
  __shared__ u16 Ks[2][64 * 64];     // [key][d-chunk^key&7]
  __shared__ u16 Vts[2][64 * 64];    // [d][sigma-chunk^d&7]
  __shared__ u16 Ps[4][32 * 64];     // per-wave P [row][sigma-chunk^row&7]

  int tid = threadIdx.x, wave = tid >> 6, lane = tid & 63;
  int quad = lane >> 4, l16 = lane & 15;
  int bh = blockIdx.x;
  int b = bh >> 4, h = bh & 15;
  int q0 = blockIdx.y * 128 + wave * 32;
  size_t gbase = (size_t)b * SEQ * D_MODEL;
  const u16* kbase = Kp + gbase + (size_t)h * HEAD_DIM;
  const u16* vbase = Vt + (size_t)bh * HEAD_DIM * SEQ;
  const u16* qrow = Q + gbase + (size_t)q0 * D_MODEL + (size_t)h * HEAD_DIM;

  // Q A-frags (scale pre-folded): aq[rowset][k-half]
  short8 aq[2][2];
#pragma unroll
  for (int rs = 0; rs < 2; ++rs)
#pragma unroll
    for (int dc = 0; dc < 2; ++dc)
      aq[rs][dc] = *(const short8*)(qrow + (size_t)(rs * 16 + l16) * D_MODEL + dc * 32 + quad * 8);

  f32x4 Oacc[2][4];
  float lpart[2][4];
#pragma unroll
  for (int rs = 0; rs < 2; ++rs)
#pragma unroll
    for (int ni = 0; ni < 4; ++ni) Oacc[rs][ni] = f32x4{0.f, 0.f, 0.f, 0.f};
#pragma unroll
  for (int rs = 0; rs < 2; ++rs)
#pragma unroll
    for (int r = 0; r < 4; ++r) lpart[rs][r] = 0.f;

  // staging offsets (u16 units), chunk c = i*256 + tid
  size_t koff[2], voff[2];
  int dstoff[2];
#pragma unroll
  for (int i = 0; i < 2; ++i) {
    int c = i * 256 + tid;
    int krow = c >> 3, kgp = c & 7;
    koff[i] = (size_t)krow * D_MODEL + (size_t)((kgp ^ (krow & 7)) * 8);
    voff[i] = (size_t)krow * SEQ + (size_t)((kgp ^ (krow & 7)) * 8);
    dstoff[i] = i * 4096 + wave * 1024;  // bytes
  }

  // prologue: stage tile 0 into buffer 0
#pragma unroll
  for (int i = 0; i < 2; ++i) {
    async_lds16(kbase + koff[i], (char*)Ks[0] + dstoff[i]);
    async_lds16(vbase + voff[i], (char*)Vts[0] + dstoff[i]);
  }

  constexpr int NT = SEQ / 64;  // 32 tiles
  for (int t = 0; t < NT; ++t) {
    int cur = t & 1;
    __syncthreads();  // drains tile t staging (vmcnt0+lgkm0); closes reads of buf[cur^1]
    if (t + 1 < NT) {
      size_t kvoff = (size_t)(t + 1) * 64;
#pragma unroll
      for (int i = 0; i < 2; ++i) {
        async_lds16(kbase + kvoff * D_MODEL + koff[i], (char*)Ks[cur ^ 1] + dstoff[i]);
        async_lds16(vbase + kvoff + voff[i], (char*)Vts[cur ^ 1] + dstoff[i]);
      }
    }

    const u16* Kc = Ks[cur];
    const u16* Vc = Vts[cur];
    u16* Pw = Ps[wave];
    int x = l16 & 7;

    // K B-frags hoisted (shared across both row-sets)
    short8 kf[4][2];
#pragma unroll
    for (int sub = 0; sub < 4; ++sub) {
      const u16* kr = Kc + (sub * 16 + l16) * 64;
      kf[sub][0] = *(const short8*)(kr + ((quad ^ x) << 3));
      kf[sub][1] = *(const short8*)(kr + (((4 + quad) ^ x) << 3));
    }

#pragma unroll
    for (int rs = 0; rs < 2; ++rs) {
      f32x4 S[4];
#pragma unroll
      for (int sub = 0; sub < 4; ++sub) {
        f32x4 s = f32x4{0.f, 0.f, 0.f, 0.f};
        s = __builtin_amdgcn_mfma_f32_16x16x32_bf16(aq[rs][0], kf[sub][0], s, 0, 0, 0);
        s = __builtin_amdgcn_mfma_f32_16x16x32_bf16(aq[rs][1], kf[sub][1], s, 0, 0, 0);
        S[sub] = s;
      }
#pragma unroll
      for (int r = 0; r < 4; ++r) {
        float p0 = __builtin_amdgcn_exp2f(S[0][r]);
        float p1 = __builtin_amdgcn_exp2f(S[1][r]);
        float p2 = __builtin_amdgcn_exp2f(S[2][r]);
        float p3 = __builtin_amdgcn_exp2f(S[3][r]);
        lpart[rs][r] += (p0 + p1) + (p2 + p3);
        u32 lo = pack_bf16(p0, p1);
        u32 hi = pack_bf16(p2, p3);
        int row = rs * 16 + quad * 4 + r;
        int off = row * 64 + (((l16 >> 1) ^ (row & 7)) << 3) + ((l16 & 1) << 2);
        *(u32x2*)(Pw + off) = u32x2{lo, hi};
      }
    }

    // PV: O += P * V (sigma-space K-dim consistent between P and Vt)
#pragma unroll
    for (int kc = 0; kc < 2; ++kc) {
      short8 pa[2];
#pragma unroll
      for (int rs = 0; rs < 2; ++rs) {
        int prow = rs * 16 + l16;
        pa[rs] = *(const short8*)(Pw + prow * 64 + ((((kc << 2) + quad) ^ x) << 3));
      }
#pragma unroll
      for (int ni = 0; ni < 4; ++ni) {
        int d = ni * 16 + l16;
        short8 bv = *(const short8*)(Vc + d * 64 + ((((kc << 2) + quad) ^ (l16 & 7)) << 3));
        Oacc[0][ni] = __builtin_amdgcn_mfma_f32_16x16x32_bf16(pa[0], bv, Oacc[0][ni], 0, 0, 0);
        Oacc[1][ni] = __builtin_amdgcn_mfma_f32_16x16x32_bf16(pa[1], bv, Oacc[1][ni], 0, 0, 0);
      }
    }
  }

  // epilogue: reduce l across the 16 key-lanes, normalize, store bf16
#pragma unroll
  for (int rs = 0; rs < 2; ++rs)
#pragma unroll
    for (int r = 0; r < 4; ++r) {
      float l = lpart[rs][r];
      l += __shfl_xor(l, 1);
      l += __shfl_xor(l, 2);
      l += __shfl_xor(l, 4);
      l += __shfl_xor(l, 8);
      float inv = 1.0f / l;
      size_t orow = gbase + (size_t)(q0 + rs * 16 + quad * 4 + r) * D_MODEL + (size_t)h * HEAD_DIM;
#pragma unroll
      for (int ni = 0; ni < 4; ++ni)
        Outp[orow + ni * 16 + l16] = f2b(Oacc[rs][ni][r] * inv);
    }
}

// ---------------- launch ----------------
extern "C" void kernel_launch(void* const* d_in, const int* in_sizes, int n_in,
                              void* d_out, int out_size, void* d_ws, size_t ws_size,
                              hipStream_t stream) {
  const float* x  = (const float*)d_in[0];
  const float* y  = (const float*)d_in[1];
  const float* wq = (const float*)d_in[2];
  const float* bq = (const float*)d_in[3];
  const float* wk = (const float*)d_in[4];
  const float* bk = (const float*)d_in[5];
  const float* wv = (const float*)d_in[6];
  const float* bv = (const float*)d_in[7];
  const float* wo = (const float*)d_in[8];
  const float* bo = (const float*)d_in[9];
  float* out = (float*)d_out;

  char* ws = (char*)d_ws;
  const size_t SZ_ACT = (size_t)ROWS * D_MODEL * 2;     // 16 MiB
  const size_t SZ_W   = (size_t)D_MODEL * D_MODEL * 2;  // 2 MiB
  u16* xb  = (u16*)(ws);
  u16* yb  = (u16*)(ws + SZ_ACT);
  u16* wT  = (u16*)(ws + 2 * SZ_ACT);                   // wq,wk,wv,wo transposed, contiguous
  u16* wqT = wT;
  u16* wkT = (u16*)(ws + 2 * SZ_ACT + SZ_W);
  u16* wvT = (u16*)(ws + 2 * SZ_ACT + 2 * SZ_W);
  u16* woT = (u16*)(ws + 2 * SZ_ACT + 3 * SZ_W);
  u16* qb  = (u16*)(ws + 2 * SZ_ACT + 4 * SZ_W);
  u16* kb  = (u16*)(ws + 3 * SZ_ACT + 4 * SZ_W);
  u16* vt  = (u16*)(ws + 4 * SZ_ACT + 4 * SZ_W);
  u16* ao  = (u16*)(ws + 5 * SZ_ACT + 4 * SZ_W);

  cvt_kernel<<<dim3(8192, 2), 256, 0, stream>>>(x, y, xb, yb);
  wtrans_kernel<<<dim3(16, 16, 4), 256, 0, stream>>>(wq, wk, wv, wo, wT);
  gemm_qkv_kernel<<<dim3(512, 3), 256, 0, stream>>>(xb, yb, wqT, wkT, wvT, bq, bk, bv, qb, kb, vt);
  attn_kernel<<<dim3(64, 16), 256, 0, stream>>>(qb, kb, vt, ao);
  gemm_o_kernel<<<dim3(8, 64), 256, 0, stream>>>(ao, woT, bo, out);
}

// Round 4
// 329.810 us; speedup vs baseline: 1.0680x; 1.0680x over previous
//
#include <hip/hip_runtime.h>
#include <stdint.h>

#define D_MODEL 1024
#define NHEAD 16
#define HEAD_DIM 64
#define BATCH 4
#define SEQ 2048
#define ROWS (BATCH*SEQ)   // 8192

typedef __attribute__((ext_vector_type(8))) short short8;
typedef __attribute__((ext_vector_type(4))) float f32x4;
typedef __attribute__((ext_vector_type(2))) unsigned int u32x2;
typedef unsigned short u16;
typedef unsigned int u32;

// log2(e)/8 folded into Q at projection time
#define QSCALE 0.18033688011112042f

// fp32 -> bf16 round-to-nearest-even
__device__ __forceinline__ u16 f2b(float f) {
  union { float f; uint32_t u; } in; in.f = f;
  uint32_t u = in.u;
  return (u16)((u + 0x7FFFu + ((u >> 16) & 1u)) >> 16);
}

// async global->LDS, 16B/lane; HW dest = wave-uniform base + lane*16
__device__ __forceinline__ void async_lds16(const void* g, void* l) {
  __builtin_amdgcn_global_load_lds(
      (const __attribute__((address_space(1))) uint32_t*)g,
      (__attribute__((address_space(3))) uint32_t*)l,
      16, 0, 0);
}

// pack two f32 into bf16x2 (round-half-up)
__device__ __forceinline__ u32 pack_bf16(float lo, float hi) {
  union { float f; uint32_t u; } a, b; a.f = lo; b.f = hi;
  return __builtin_amdgcn_perm(b.u + 0x8000u, a.u + 0x8000u, 0x07060302u);
}

// ---------------- fp32 -> bf16 bulk convert (x and y fused) ----------------
__global__ void __launch_bounds__(256) cvt_kernel(const float* __restrict__ x,
                                                  const float* __restrict__ y,
                                                  u16* __restrict__ xb,
                                                  u16* __restrict__ yb) {
  const float* in = blockIdx.y ? y : x;
  u16* out = blockIdx.y ? yb : xb;
  int i = blockIdx.x * 256 + threadIdx.x;
  float4 v = ((const float4*)in)[i];
  ushort4 o;
  o.x = f2b(v.x); o.y = f2b(v.y); o.z = f2b(v.z); o.w = f2b(v.w);
  ((ushort4*)out)[i] = o;
}

// ---------------- weight transpose + convert (4 weights fused via z) ----------------
__global__ void __launch_bounds__(256) wtrans_kernel(const float* __restrict__ wq,
                                                     const float* __restrict__ wk,
                                                     const float* __restrict__ wv,
                                                     const float* __restrict__ wo,
                                                     u16* __restrict__ wtbase) {
  __shared__ u16 tile[64 * 65];
  int z = blockIdx.z;
  const float* w = (z == 0) ? wq : (z == 1 ? wk : (z == 2 ? wv : wo));
  u16* wt = wtbase + (size_t)z * D_MODEL * D_MODEL;
  int t = threadIdx.x;
  int c = t & 63, rb = t >> 6;
  int k0 = blockIdx.x * 64, n0 = blockIdx.y * 64;
#pragma unroll
  for (int i = 0; i < 16; ++i) {
    int r = rb + i * 4;
    tile[c * 65 + r] = f2b(w[(size_t)(k0 + r) * D_MODEL + n0 + c]);
  }
  __syncthreads();
#pragma unroll
  for (int i = 0; i < 16; ++i) {
    int r = rb + i * 4;
    wt[(size_t)(n0 + r) * D_MODEL + k0 + c] = tile[r * 65 + c];
  }
}

// ---------------- GEMM core: C[M][N] = A[M][K] * Bt[N][K]^T + bias ----------------
// BK=64 (two 32-k halves per barrier). 128x128 tile, 4 waves (2x2), 4x4 accs.
// MODE 0 (bf16 out) / MODE 1 (f32 out): OPERAND-SWAPPED (weights in MFMA-A slot)
//   so D's reg-dim = output columns -> vectorized 8B/16B stores.
// MODE 2: V^T sigma-layout out, natural orientation, packed across ni.
template <int MODE>
__device__ __forceinline__ void gemm_bt_core(const u16* __restrict__ A,
                                             const u16* __restrict__ Bt,
                                             const float* __restrict__ bias,
                                             void* __restrict__ Cout, float scale,
                                             int m0, int n0) {
  constexpr int K = 1024, N = 1024;
  constexpr bool SWAP = (MODE != 2);
  __shared__ u16 As[2][128 * 32];
  __shared__ u16 Bs[2][128 * 32];
  int tid = threadIdx.x;
  int wave = tid >> 6, lane = tid & 63;
  int quad = lane >> 4, l16 = lane & 15;
  int wm = wave & 1, wn = wave >> 1;

  f32x4 acc[4][4];
#pragma unroll
  for (int p = 0; p < 4; ++p)
#pragma unroll
    for (int q = 0; q < 4; ++q) acc[p][q] = f32x4{0.f, 0.f, 0.f, 0.f};

  int srow = lane >> 2;
  int scol = (lane & 3) * 16;

  for (int k0 = 0; k0 < K; k0 += 64) {
#pragma unroll
    for (int kh = 0; kh < 2; ++kh) {
#pragma unroll
      for (int i = 0; i < 2; ++i) {
        int c = wave * 2 + i;
        const char* ga = (const char*)(A + (size_t)(m0 + c * 16 + srow) * K + k0 + kh * 32) + scol;
        async_lds16(ga, (char*)As[kh] + c * 1024);
        const char* gb = (const char*)(Bt + (size_t)(n0 + c * 16 + srow) * K + k0 + kh * 32) + scol;
        async_lds16(gb, (char*)Bs[kh] + c * 1024);
      }
    }
    __syncthreads();  // drains staging

#pragma unroll
    for (int kh = 0; kh < 2; ++kh) {
      short8 fa[4], fb[4];
#pragma unroll
      for (int p = 0; p < 4; ++p)
        fa[p] = SWAP
          ? *(const short8*)(Bs[kh] + (wn * 64 + p * 16 + l16) * 32 + quad * 8)
          : *(const short8*)(As[kh] + (wm * 64 + p * 16 + l16) * 32 + quad * 8);
#pragma unroll
      for (int q = 0; q < 4; ++q)
        fb[q] = SWAP
          ? *(const short8*)(As[kh] + (wm * 64 + q * 16 + l16) * 32 + quad * 8)
          : *(const short8*)(Bs[kh] + (wn * 64 + q * 16 + l16) * 32 + quad * 8);
#pragma unroll
      for (int p = 0; p < 4; ++p)
#pragma unroll
        for (int q = 0; q < 4; ++q)
          acc[p][q] = __builtin_amdgcn_mfma_f32_16x16x32_bf16(fa[p], fb[q], acc[p][q], 0, 0, 0);
    }
    __syncthreads();
  }

  if (MODE == 2) {
    // acc[p][q]: D-row (quad*4+r) = d-dim (wvT row), D-col (l16) = s within q*16 block.
    int sblk = n0 + wn * 64;               // 64-aligned s block; all s in same batch b
    int bb = sblk >> 11;
    int ssb = sblk & 2047;
#pragma unroll
    for (int p = 0; p < 4; ++p) {
      int dbase = m0 + wm * 64 + p * 16 + quad * 4;
      float4 b4 = *(const float4*)(bias + dbase);
#pragma unroll
      for (int r = 0; r < 4; ++r) {
        int d = dbase + r;
        float bv = ((const float*)&b4)[r];
        u32 lo = pack_bf16(acc[p][0][r] + bv, acc[p][1][r] + bv);
        u32 hi = pack_bf16(acc[p][2][r] + bv, acc[p][3][r] + bv);
        size_t vtrow = ((size_t)bb * 16 + (d >> 6)) * 64 + (d & 63);
        *(u32x2*)((u16*)Cout + vtrow * 2048 + ssb + 4 * l16) = u32x2{lo, hi};
      }
    }
  } else {
    // SWAPPED: acc[p][q]: D-row (quad*4+r) = out-col n, D-col (l16) = out-row m.
#pragma unroll
    for (int p = 0; p < 4; ++p) {
      int nbase = n0 + wn * 64 + p * 16 + quad * 4;
      float4 b4 = *(const float4*)(bias + nbase);
#pragma unroll
      for (int q = 0; q < 4; ++q) {
        size_t mrow = (size_t)(m0 + wm * 64 + q * 16 + l16);
        float v0 = (acc[p][q][0] + b4.x) * scale;
        float v1 = (acc[p][q][1] + b4.y) * scale;
        float v2 = (acc[p][q][2] + b4.z) * scale;
        float v3 = (acc[p][q][3] + b4.w) * scale;
        if (MODE == 1) {
          *(f32x4*)((float*)Cout + mrow * N + nbase) = f32x4{v0, v1, v2, v3};
        } else {
          *(u32x2*)((u16*)Cout + mrow * N + nbase) = u32x2{pack_bf16(v0, v1), pack_bf16(v2, v3)};
        }
      }
    }
  }
}

// QKV fused: grid (512, 3). z=0: Q=x*wq (scaled); z=1: K=y*wk; z=2: V^T sigma
__global__ void __launch_bounds__(256, 4) gemm_qkv_kernel(
    const u16* __restrict__ xb, const u16* __restrict__ yb,
    const u16* __restrict__ wqT, const u16* __restrict__ wkT, const u16* __restrict__ wvT,
    const float* __restrict__ bq, const float* __restrict__ bk, const float* __restrict__ bv,
    u16* __restrict__ q, u16* __restrict__ k, u16* __restrict__ vt) {
  int bx = blockIdx.x, z = blockIdx.y;
  if (z == 0) {
    gemm_bt_core<0>(xb, wqT, bq, q, QSCALE, (bx >> 3) * 128, (bx & 7) * 128);
  } else if (z == 1) {
    gemm_bt_core<0>(yb, wkT, bk, k, 1.0f, (bx >> 3) * 128, (bx & 7) * 128);
  } else {
    gemm_bt_core<2>(wvT, yb, bv, vt, 1.0f, (bx & 7) * 128, (bx >> 3) * 128);
  }
}

__global__ void __launch_bounds__(256, 4) gemm_o_kernel(const u16* __restrict__ ao,
                                                        const u16* __restrict__ woT,
                                                        const float* __restrict__ bo,
                                                        float* __restrict__ out) {
  gemm_bt_core<1>(ao, woT, bo, out, 1.0f, blockIdx.y * 128, blockIdx.x * 128);
}

// ---------------- flash attention, no-max softmax, single-buffer (R2 structure) ----
// grid (B*H, SEQ/128): bh-major -> all q-blocks of one bh share an XCD's L2 KV.
// Block 256 = 4 waves; wave owns 32 q-rows; kv-tile 64 keys.
__global__ void __launch_bounds__(256, 4) attn_kernel(const u16* __restrict__ Q,
                                                      const u16* __restrict__ Kp,
                                                      const u16* __restrict__ Vt,
                                                      u16* __restrict__ Outp) {
  __shared__ u16 Ks[64 * 64];        // [key][d-chunk^key&7]
  __shared__ u16 Vts[64 * 64];       // [d][sigma-chunk^d&7]
  __shared__ u16 Ps[4][32 * 64];     // per-wave P [row][sigma-chunk^row&7]

  int tid = threadIdx.x, wave = tid >> 6, lane = tid & 63;
  int quad = lane >> 4, l16 = lane & 15;
  int bh = blockIdx.x;
  int b = bh >> 4, h = bh & 15;
  int q0 = blockIdx.y * 128 + wave * 32;
  size_t gbase = (size_t)b * SEQ * D_MODEL;
  const u16* kbase = Kp + gbase + (size_t)h * HEAD_DIM;
  const u16* vbase = Vt + (size_t)bh * HEAD_DIM * SEQ;
  const u16* qrow = Q + gbase + (size_t)q0 * D_MODEL + (size_t)h * HEAD_DIM;

  // Q A-frags (scale pre-folded): aq[rowset][k-half]
  short8 aq[2][2];
#pragma unroll
  for (int rs = 0; rs < 2; ++rs)
#pragma unroll
    for (int dc = 0; dc < 2; ++dc)
      aq[rs][dc] = *(const short8*)(qrow + (size_t)(rs * 16 + l16) * D_MODEL + dc * 32 + quad * 8);

  f32x4 Oacc[2][4];
  float lpart[2][4];
#pragma unroll
  for (int rs = 0; rs < 2; ++rs)
#pragma unroll
    for (int ni = 0; ni < 4; ++ni) Oacc[rs][ni] = f32x4{0.f, 0.f, 0.f, 0.f};
#pragma unroll
  for (int rs = 0; rs < 2; ++rs)
#pragma unroll
    for (int r = 0; r < 4; ++r) lpart[rs][r] = 0.f;

  // staging offsets (u16 units), chunk c = i*256 + tid
  size_t koff[2], voff[2];
  int dstoff[2];
#pragma unroll
  for (int i = 0; i < 2; ++i) {
    int c = i * 256 + tid;
    int krow = c >> 3, kgp = c & 7;
    koff[i] = (size_t)krow * D_MODEL + (size_t)((kgp ^ (krow & 7)) * 8);
    voff[i] = (size_t)krow * SEQ + (size_t)((kgp ^ (krow & 7)) * 8);
    dstoff[i] = i * 4096 + wave * 1024;  // bytes
  }

  for (int kv0 = 0; kv0 < SEQ; kv0 += 64) {
    __syncthreads();  // all waves done reading previous tile
#pragma unroll
    for (int i = 0; i < 2; ++i) {
      async_lds16(kbase + (size_t)kv0 * D_MODEL + koff[i], (char*)Ks + dstoff[i]);
      async_lds16(vbase + (size_t)kv0 + voff[i], (char*)Vts + dstoff[i]);
    }
    __syncthreads();  // staging complete

    u16* Pw = Ps[wave];
    int x = l16 & 7;

    // K B-frags hoisted (shared across both row-sets)
    short8 kf[4][2];
#pragma unroll
    for (int sub = 0; sub < 4; ++sub) {
      const u16* kr = Ks + (sub * 16 + l16) * 64;
      kf[sub][0] = *(const short8*)(kr + ((quad ^ x) << 3));
      kf[sub][1] = *(const short8*)(kr + (((4 + quad) ^ x) << 3));
    }

#pragma unroll
    for (int rs = 0; rs < 2; ++rs) {
      f32x4 S[4];
#pragma unroll
      for (int sub = 0; sub < 4; ++sub) {
        f32x4 s = f32x4{0.f, 0.f, 0.f, 0.f};
        s = __builtin_amdgcn_mfma_f32_16x16x32_bf16(aq[rs][0], kf[sub][0], s, 0, 0, 0);
        s = __builtin_amdgcn_mfma_f32_16x16x32_bf16(aq[rs][1], kf[sub][1], s, 0, 0, 0);
        S[sub] = s;
      }
#pragma unroll
      for (int r = 0; r < 4; ++r) {
        float p0 = __builtin_amdgcn_exp2f(S[0][r]);
        float p1 = __builtin_amdgcn_exp2f(S[1][r]);
        float p2 = __builtin_amdgcn_exp2f(S[2][r]);
        float p3 = __builtin_amdgcn_exp2f(S[3][r]);
        lpart[rs][r] += (p0 + p1) + (p2 + p3);
        u32 lo = pack_bf16(p0, p1);
        u32 hi = pack_bf16(p2, p3);
        int row = rs * 16 + quad * 4 + r;
        int off = row * 64 + (((l16 >> 1) ^ (row & 7)) << 3) + ((l16 & 1) << 2);
        *(u32x2*)(Pw + off) = u32x2{lo, hi};
      }
    }

    // PV: O += P * V (sigma-space K-dim consistent between P and Vt)
#pragma unroll
    for (int kc = 0; kc < 2; ++kc) {
      short8 pa[2];
#pragma unroll
      for (int rs = 0; rs < 2; ++rs) {
        int prow = rs * 16 + l16;
        pa[rs] = *(const short8*)(Pw + prow * 64 + ((((kc << 2) + quad) ^ x) << 3));
      }
#pragma unroll
      for (int ni = 0; ni < 4; ++ni) {
        int d = ni * 16 + l16;
        short8 bv = *(const short8*)(Vts + d * 64 + ((((kc << 2) + quad) ^ (l16 & 7)) << 3));
        Oacc[0][ni] = __builtin_amdgcn_mfma_f32_16x16x32_bf16(pa[0], bv, Oacc[0][ni], 0, 0, 0);
        Oacc[1][ni] = __builtin_amdgcn_mfma_f32_16x16x32_bf16(pa[1], bv, Oacc[1][ni], 0, 0, 0);
      }
    }
  }

  // epilogue: reduce l across the 16 key-lanes, normalize, store bf16
#pragma unroll
  for (int rs = 0; rs < 2; ++rs)
#pragma unroll
    for (int r = 0; r < 4; ++r) {
      float l = lpart[rs][r];
      l += __shfl_xor(l, 1);
      l += __shfl_xor(l, 2);
      l += __shfl_xor(l, 4);
      l += __shfl_xor(l, 8);
      float inv = 1.0f / l;
      size_t orow = gbase + (size_t)(q0 + rs * 16 + quad * 4 + r) * D_MODEL + (size_t)h * HEAD_DIM;
#pragma unroll
      for (int ni = 0; ni < 4; ++ni)
        Outp[orow + ni * 16 + l16] = f2b(Oacc[rs][ni][r] * inv);
    }
}

// ---------------- launch ----------------
extern "C" void kernel_launch(void* const* d_in, const int* in_sizes, int n_in,
                              void* d_out, int out_size, void* d_ws, size_t ws_size,
                              hipStream_t stream) {
  const float* x  = (const float*)d_in[0];
  const float* y  = (const float*)d_in[1];
  const float* wq = (const float*)d_in[2];
  const float* bq = (const float*)d_in[3];
  const float* wk = (const float*)d_in[4];
  const float* bk = (const float*)d_in[5];
  const float* wv = (const float*)d_in[6];
  const float* bv = (const float*)d_in[7];
  const float* wo = (const float*)d_in[8];
  const float* bo = (const float*)d_in[9];
  float* out = (float*)d_out;

  char* ws = (char*)d_ws;
  const size_t SZ_ACT = (size_t)ROWS * D_MODEL * 2;     // 16 MiB
  const size_t SZ_W   = (size_t)D_MODEL * D_MODEL * 2;  // 2 MiB
  u16* xb  = (u16*)(ws);
  u16* yb  = (u16*)(ws + SZ_ACT);
  u16* wT  = (u16*)(ws + 2 * SZ_ACT);
  u16* wqT = wT;
  u16* wkT = (u16*)(ws + 2 * SZ_ACT + SZ_W);
  u16* wvT = (u16*)(ws + 2 * SZ_ACT + 2 * SZ_W);
  u16* woT = (u16*)(ws + 2 * SZ_ACT + 3 * SZ_W);
  u16* qb  = (u16*)(ws + 2 * SZ_ACT + 4 * SZ_W);
  u16* kb  = (u16*)(ws + 3 * SZ_ACT + 4 * SZ_W);
  u16* vt  = (u16*)(ws + 4 * SZ_ACT + 4 * SZ_W);
  u16* ao  = (u16*)(ws + 5 * SZ_ACT + 4 * SZ_W);

  cvt_kernel<<<dim3(8192, 2), 256, 0, stream>>>(x, y, xb, yb);
  wtrans_kernel<<<dim3(16, 16, 4), 256, 0, stream>>>(wq, wk, wv, wo, wT);
  gemm_qkv_kernel<<<dim3(512, 3), 256, 0, stream>>>(xb, yb, wqT, wkT, wvT, bq, bk, bv, qb, kb, vt);
  attn_kernel<<<dim3(64, 16), 256, 0, stream>>>(qb, kb, vt, ao);
  gemm_o_kernel<<<dim3(8, 64), 256, 0, stream>>>(ao, woT, bo, out);
}

// Round 5
// 327.618 us; speedup vs baseline: 1.0751x; 1.0067x over previous
//
#include <hip/hip_runtime.h>
#include <stdint.h>

#define D_MODEL 1024
#define NHEAD 16
#define HEAD_DIM 64
#define BATCH 4
#define SEQ 2048
#define ROWS (BATCH*SEQ)   // 8192

typedef __attribute__((ext_vector_type(8))) short short8;
typedef __attribute__((ext_vector_type(4))) float f32x4;
typedef __attribute__((ext_vector_type(2))) unsigned int u32x2;
typedef unsigned short u16;
typedef unsigned int u32;

// log2(e)/8 folded into Q at projection time
#define QSCALE 0.18033688011112042f

// fp32 -> bf16 round-to-nearest-even
__device__ __forceinline__ u16 f2b(float f) {
  union { float f; uint32_t u; } in; in.f = f;
  uint32_t u = in.u;
  return (u16)((u + 0x7FFFu + ((u >> 16) & 1u)) >> 16);
}

// async global->LDS, 16B/lane; HW dest = wave-uniform base + lane*16
__device__ __forceinline__ void async_lds16(const void* g, void* l) {
  __builtin_amdgcn_global_load_lds(
      (const __attribute__((address_space(1))) uint32_t*)g,
      (__attribute__((address_space(3))) uint32_t*)l,
      16, 0, 0);
}

// pack two f32 into bf16x2 (round-half-up)
__device__ __forceinline__ u32 pack_bf16(float lo, float hi) {
  union { float f; uint32_t u; } a, b; a.f = lo; b.f = hi;
  return __builtin_amdgcn_perm(b.u + 0x8000u, a.u + 0x8000u, 0x07060302u);
}

// ---------------- fp32 -> bf16 bulk convert (x and y fused) ----------------
__global__ void __launch_bounds__(256) cvt_kernel(const float* __restrict__ x,
                                                  const float* __restrict__ y,
                                                  u16* __restrict__ xb,
                                                  u16* __restrict__ yb) {
  const float* in = blockIdx.y ? y : x;
  u16* out = blockIdx.y ? yb : xb;
  int i = blockIdx.x * 256 + threadIdx.x;
  float4 v = ((const float4*)in)[i];
  ushort4 o;
  o.x = f2b(v.x); o.y = f2b(v.y); o.z = f2b(v.z); o.w = f2b(v.w);
  ((ushort4*)out)[i] = o;
}

// ---------------- weight transpose + convert (4 weights fused via z) ----------------
__global__ void __launch_bounds__(256) wtrans_kernel(const float* __restrict__ wq,
                                                     const float* __restrict__ wk,
                                                     const float* __restrict__ wv,
                                                     const float* __restrict__ wo,
                                                     u16* __restrict__ wtbase) {
  __shared__ u16 tile[64 * 65];
  int z = blockIdx.z;
  const float* w = (z == 0) ? wq : (z == 1 ? wk : (z == 2 ? wv : wo));
  u16* wt = wtbase + (size_t)z * D_MODEL * D_MODEL;
  int t = threadIdx.x;
  int c = t & 63, rb = t >> 6;
  int k0 = blockIdx.x * 64, n0 = blockIdx.y * 64;
#pragma unroll
  for (int i = 0; i < 16; ++i) {
    int r = rb + i * 4;
    tile[c * 65 + r] = f2b(w[(size_t)(k0 + r) * D_MODEL + n0 + c]);
  }
  __syncthreads();
#pragma unroll
  for (int i = 0; i < 16; ++i) {
    int r = rb + i * 4;
    wt[(size_t)(n0 + r) * D_MODEL + k0 + c] = tile[r * 65 + c];
  }
}

// ---------------- GEMM core: C[M][N] = A[M][K] * Bt[N][K]^T + bias ----------------
// BK=64 (two 32-k halves per barrier). 128x128 tile, 4 waves (2x2), 4x4 accs.
// MODE 0 (bf16 out) / MODE 1 (f32 out): OPERAND-SWAPPED (weights in MFMA-A slot)
//   so D's reg-dim = output columns -> vectorized 8B/16B stores.
// MODE 2: V^T sigma-layout out, natural orientation, packed across ni.
template <int MODE>
__device__ __forceinline__ void gemm_bt_core(const u16* __restrict__ A,
                                             const u16* __restrict__ Bt,
                                             const float* __restrict__ bias,
                                             void* __restrict__ Cout, float scale,
                                             int m0, int n0) {
  constexpr int K = 1024, N = 1024;
  constexpr bool SWAP = (MODE != 2);
  __shared__ u16 As[2][128 * 32];
  __shared__ u16 Bs[2][128 * 32];
  int tid = threadIdx.x;
  int wave = tid >> 6, lane = tid & 63;
  int quad = lane >> 4, l16 = lane & 15;
  int wm = wave & 1, wn = wave >> 1;

  f32x4 acc[4][4];
#pragma unroll
  for (int p = 0; p < 4; ++p)
#pragma unroll
    for (int q = 0; q < 4; ++q) acc[p][q] = f32x4{0.f, 0.f, 0.f, 0.f};

  int srow = lane >> 2;
  int scol = (lane & 3) * 16;

  for (int k0 = 0; k0 < K; k0 += 64) {
#pragma unroll
    for (int kh = 0; kh < 2; ++kh) {
#pragma unroll
      for (int i = 0; i < 2; ++i) {
        int c = wave * 2 + i;
        const char* ga = (const char*)(A + (size_t)(m0 + c * 16 + srow) * K + k0 + kh * 32) + scol;
        async_lds16(ga, (char*)As[kh] + c * 1024);
        const char* gb = (const char*)(Bt + (size_t)(n0 + c * 16 + srow) * K + k0 + kh * 32) + scol;
        async_lds16(gb, (char*)Bs[kh] + c * 1024);
      }
    }
    __syncthreads();  // drains staging

#pragma unroll
    for (int kh = 0; kh < 2; ++kh) {
      short8 fa[4], fb[4];
#pragma unroll
      for (int p = 0; p < 4; ++p)
        fa[p] = SWAP
          ? *(const short8*)(Bs[kh] + (wn * 64 + p * 16 + l16) * 32 + quad * 8)
          : *(const short8*)(As[kh] + (wm * 64 + p * 16 + l16) * 32 + quad * 8);
#pragma unroll
      for (int q = 0; q < 4; ++q)
        fb[q] = SWAP
          ? *(const short8*)(As[kh] + (wm * 64 + q * 16 + l16) * 32 + quad * 8)
          : *(const short8*)(Bs[kh] + (wn * 64 + q * 16 + l16) * 32 + quad * 8);
#pragma unroll
      for (int p = 0; p < 4; ++p)
#pragma unroll
        for (int q = 0; q < 4; ++q)
          acc[p][q] = __builtin_amdgcn_mfma_f32_16x16x32_bf16(fa[p], fb[q], acc[p][q], 0, 0, 0);
    }
    __syncthreads();
  }

  if (MODE == 2) {
    // acc[p][q]: D-row (quad*4+r) = d-dim (wvT row), D-col (l16) = s within q*16 block.
    int sblk = n0 + wn * 64;               // 64-aligned s block; all s in same batch b
    int bb = sblk >> 11;
    int ssb = sblk & 2047;
#pragma unroll
    for (int p = 0; p < 4; ++p) {
      int dbase = m0 + wm * 64 + p * 16 + quad * 4;
      float4 b4 = *(const float4*)(bias + dbase);
#pragma unroll
      for (int r = 0; r < 4; ++r) {
        int d = dbase + r;
        float bv = ((const float*)&b4)[r];
        u32 lo = pack_bf16(acc[p][0][r] + bv, acc[p][1][r] + bv);
        u32 hi = pack_bf16(acc[p][2][r] + bv, acc[p][3][r] + bv);
        size_t vtrow = ((size_t)bb * 16 + (d >> 6)) * 64 + (d & 63);
        *(u32x2*)((u16*)Cout + vtrow * 2048 + ssb + 4 * l16) = u32x2{lo, hi};
      }
    }
  } else {
    // SWAPPED: acc[p][q]: D-row (quad*4+r) = out-col n, D-col (l16) = out-row m.
#pragma unroll
    for (int p = 0; p < 4; ++p) {
      int nbase = n0 + wn * 64 + p * 16 + quad * 4;
      float4 b4 = *(const float4*)(bias + nbase);
#pragma unroll
      for (int q = 0; q < 4; ++q) {
        size_t mrow = (size_t)(m0 + wm * 64 + q * 16 + l16);
        float v0 = (acc[p][q][0] + b4.x) * scale;
        float v1 = (acc[p][q][1] + b4.y) * scale;
        float v2 = (acc[p][q][2] + b4.z) * scale;
        float v3 = (acc[p][q][3] + b4.w) * scale;
        if (MODE == 1) {
          *(f32x4*)((float*)Cout + mrow * N + nbase) = f32x4{v0, v1, v2, v3};
        } else {
          *(u32x2*)((u16*)Cout + mrow * N + nbase) = u32x2{pack_bf16(v0, v1), pack_bf16(v2, v3)};
        }
      }
    }
  }
}

// QKV fused: grid (512, 3). z=0: Q=x*wq (scaled); z=1: K=y*wk; z=2: V^T sigma
__global__ void __launch_bounds__(256, 4) gemm_qkv_kernel(
    const u16* __restrict__ xb, const u16* __restrict__ yb,
    const u16* __restrict__ wqT, const u16* __restrict__ wkT, const u16* __restrict__ wvT,
    const float* __restrict__ bq, const float* __restrict__ bk, const float* __restrict__ bv,
    u16* __restrict__ q, u16* __restrict__ k, u16* __restrict__ vt) {
  int bx = blockIdx.x, z = blockIdx.y;
  if (z == 0) {
    gemm_bt_core<0>(xb, wqT, bq, q, QSCALE, (bx >> 3) * 128, (bx & 7) * 128);
  } else if (z == 1) {
    gemm_bt_core<0>(yb, wkT, bk, k, 1.0f, (bx >> 3) * 128, (bx & 7) * 128);
  } else {
    gemm_bt_core<2>(wvT, yb, bv, vt, 1.0f, (bx & 7) * 128, (bx >> 3) * 128);
  }
}

__global__ void __launch_bounds__(256, 4) gemm_o_kernel(const u16* __restrict__ ao,
                                                        const u16* __restrict__ woT,
                                                        const float* __restrict__ bo,
                                                        float* __restrict__ out) {
  gemm_bt_core<1>(ao, woT, bo, out, 1.0f, blockIdx.y * 128, blockIdx.x * 128);
}

// ---------------- flash attention: no-max softmax, dbuf K/V, single barrier ------
// grid (B*H, SEQ/128): bh-major -> all q-blocks of one bh share an XCD's L2 KV.
// Block 256 = 4 waves; wave owns 32 q-rows (2 rowsets of 16); kv-tile 64 keys.
// K-loop: { barrier (drains tile t staging, closes buf[t+1&1] reads);
//           issue prefetch t+1 -> buf[(t+1)&1]; compute tile t on buf[t&1] }.
// Ps is 2 KB/wave, reused by both rowsets sequentially (DS ops are in-order
// per wave, so rs1's overwrite cannot pass rs0's pa reads).
// LDS total = 16 (Ks dbuf) + 16 (Vts dbuf) + 8 (Ps) = 40 KB -> 4 blocks/CU.
__global__ void __launch_bounds__(256, 4) attn_kernel(const u16* __restrict__ Q,
                                                      const u16* __restrict__ Kp,
                                                      const u16* __restrict__ Vt,
                                                      u16* __restrict__ Outp) {
  __shared__ u16 Ks[2][64 * 64];     // [key][d-chunk^key&7]
  __shared__ u16 Vts[2][64 * 64];    // [d][sigma-chunk^d&7]
  __shared__ u16 Ps[4][16 * 64];     // per-wave P [row][sigma-chunk^row&7]

  int tid = threadIdx.x, wave = tid >> 6, lane = tid & 63;
  int quad = lane >> 4, l16 = lane & 15;
  int bh = blockIdx.x;
  int b = bh >> 4, h = bh & 15;
  int q0 = blockIdx.y * 128 + wave * 32;
  size_t gbase = (size_t)b * SEQ * D_MODEL;
  const u16* kbase = Kp + gbase + (size_t)h * HEAD_DIM;
  const u16* vbase = Vt + (size_t)bh * HEAD_DIM * SEQ;
  const u16* qrow = Q + gbase + (size_t)q0 * D_MODEL + (size_t)h * HEAD_DIM;

  // Q A-frags (scale pre-folded): aq[rowset][k-half]
  short8 aq[2][2];
#pragma unroll
  for (int rs = 0; rs < 2; ++rs)
#pragma unroll
    for (int dc = 0; dc < 2; ++dc)
      aq[rs][dc] = *(const short8*)(qrow + (size_t)(rs * 16 + l16) * D_MODEL + dc * 32 + quad * 8);

  f32x4 Oacc[2][4];
  float lpart[2][4];
#pragma unroll
  for (int rs = 0; rs < 2; ++rs)
#pragma unroll
    for (int ni = 0; ni < 4; ++ni) Oacc[rs][ni] = f32x4{0.f, 0.f, 0.f, 0.f};
#pragma unroll
  for (int rs = 0; rs < 2; ++rs)
#pragma unroll
    for (int r = 0; r < 4; ++r) lpart[rs][r] = 0.f;

  // staging offsets (u16 units), chunk c = i*256 + tid
  size_t koff[2], voff[2];
  int dstoff[2];
#pragma unroll
  for (int i = 0; i < 2; ++i) {
    int c = i * 256 + tid;
    int krow = c >> 3, kgp = c & 7;
    koff[i] = (size_t)krow * D_MODEL + (size_t)((kgp ^ (krow & 7)) * 8);
    voff[i] = (size_t)krow * SEQ + (size_t)((kgp ^ (krow & 7)) * 8);
    dstoff[i] = i * 4096 + wave * 1024;  // bytes within one buffer
  }

  // prologue: stage tile 0 into buffer 0
#pragma unroll
  for (int i = 0; i < 2; ++i) {
    async_lds16(kbase + koff[i], (char*)Ks[0] + dstoff[i]);
    async_lds16(vbase + voff[i], (char*)Vts[0] + dstoff[i]);
  }

  constexpr int NT = SEQ / 64;  // 32 tiles
  for (int t = 0; t < NT; ++t) {
    int cur = t & 1;
    __syncthreads();  // drains tile t staging; closes prior reads of buf[cur^1]
    if (t + 1 < NT) {
      size_t kvoff = (size_t)(t + 1) * 64;
#pragma unroll
      for (int i = 0; i < 2; ++i) {
        async_lds16(kbase + kvoff * D_MODEL + koff[i], (char*)Ks[cur ^ 1] + dstoff[i]);
        async_lds16(vbase + kvoff + voff[i], (char*)Vts[cur ^ 1] + dstoff[i]);
      }
    }

    const u16* Kc = Ks[cur];
    const u16* Vc = Vts[cur];
    u16* Pw = Ps[wave];
    int x = l16 & 7;

    // K B-frags hoisted (shared across both row-sets)
    short8 kf[4][2];
#pragma unroll
    for (int sub = 0; sub < 4; ++sub) {
      const u16* kr = Kc + (sub * 16 + l16) * 64;
      kf[sub][0] = *(const short8*)(kr + ((quad ^ x) << 3));
      kf[sub][1] = *(const short8*)(kr + (((4 + quad) ^ x) << 3));
    }

    short8 pa[2][2];  // [rs][kc]
#pragma unroll
    for (int rs = 0; rs < 2; ++rs) {
      f32x4 S[4];
#pragma unroll
      for (int sub = 0; sub < 4; ++sub) {
        f32x4 s = f32x4{0.f, 0.f, 0.f, 0.f};
        s = __builtin_amdgcn_mfma_f32_16x16x32_bf16(aq[rs][0], kf[sub][0], s, 0, 0, 0);
        s = __builtin_amdgcn_mfma_f32_16x16x32_bf16(aq[rs][1], kf[sub][1], s, 0, 0, 0);
        S[sub] = s;
      }
#pragma unroll
      for (int r = 0; r < 4; ++r) {
        float p0 = __builtin_amdgcn_exp2f(S[0][r]);
        float p1 = __builtin_amdgcn_exp2f(S[1][r]);
        float p2 = __builtin_amdgcn_exp2f(S[2][r]);
        float p3 = __builtin_amdgcn_exp2f(S[3][r]);
        lpart[rs][r] += (p0 + p1) + (p2 + p3);
        u32 lo = pack_bf16(p0, p1);
        u32 hi = pack_bf16(p2, p3);
        int row = quad * 4 + r;  // 16-row region reused by both rowsets
        int off = row * 64 + (((l16 >> 1) ^ (row & 7)) << 3) + ((l16 & 1) << 2);
        *(u32x2*)(Pw + off) = u32x2{lo, hi};
      }
      // read back this rowset's P A-frags before rs1 overwrites the region
#pragma unroll
      for (int kc = 0; kc < 2; ++kc)
        pa[rs][kc] = *(const short8*)(Pw + l16 * 64 + ((((kc << 2) + quad) ^ x) << 3));
    }

    // PV: O += P * V (sigma-space K-dim consistent between P and Vt)
#pragma unroll
    for (int kc = 0; kc < 2; ++kc) {
#pragma unroll
      for (int ni = 0; ni < 4; ++ni) {
        int d = ni * 16 + l16;
        short8 bv = *(const short8*)(Vc + d * 64 + ((((kc << 2) + quad) ^ (l16 & 7)) << 3));
        Oacc[0][ni] = __builtin_amdgcn_mfma_f32_16x16x32_bf16(pa[0][kc], bv, Oacc[0][ni], 0, 0, 0);
        Oacc[1][ni] = __builtin_amdgcn_mfma_f32_16x16x32_bf16(pa[1][kc], bv, Oacc[1][ni], 0, 0, 0);
      }
    }
  }

  // epilogue: reduce l across the 16 key-lanes, normalize, store bf16
#pragma unroll
  for (int rs = 0; rs < 2; ++rs)
#pragma unroll
    for (int r = 0; r < 4; ++r) {
      float l = lpart[rs][r];
      l += __shfl_xor(l, 1);
      l += __shfl_xor(l, 2);
      l += __shfl_xor(l, 4);
      l += __shfl_xor(l, 8);
      float inv = 1.0f / l;
      size_t orow = gbase + (size_t)(q0 + rs * 16 + quad * 4 + r) * D_MODEL + (size_t)h * HEAD_DIM;
#pragma unroll
      for (int ni = 0; ni < 4; ++ni)
        Outp[orow + ni * 16 + l16] = f2b(Oacc[rs][ni][r] * inv);
    }
}

// ---------------- launch ----------------
extern "C" void kernel_launch(void* const* d_in, const int* in_sizes, int n_in,
                              void* d_out, int out_size, void* d_ws, size_t ws_size,
                              hipStream_t stream) {
  const float* x  = (const float*)d_in[0];
  const float* y  = (const float*)d_in[1];
  const float* wq = (const float*)d_in[2];
  const float* bq = (const float*)d_in[3];
  const float* wk = (const float*)d_in[4];
  const float* bk = (const float*)d_in[5];
  const float* wv = (const float*)d_in[6];
  const float* bv = (const float*)d_in[7];
  const float* wo = (const float*)d_in[8];
  const float* bo = (const float*)d_in[9];
  float* out = (float*)d_out;

  char* ws = (char*)d_ws;
  const size_t SZ_ACT = (size_t)ROWS * D_MODEL * 2;     // 16 MiB
  const size_t SZ_W   = (size_t)D_MODEL * D_MODEL * 2;  // 2 MiB
  u16* xb  = (u16*)(ws);
  u16* yb  = (u16*)(ws + SZ_ACT);
  u16* wT  = (u16*)(ws + 2 * SZ_ACT);
  u16* wqT = wT;
  u16* wkT = (u16*)(ws + 2 * SZ_ACT + SZ_W);
  u16* wvT = (u16*)(ws + 2 * SZ_ACT + 2 * SZ_W);
  u16* woT = (u16*)(ws + 2 * SZ_ACT + 3 * SZ_W);
  u16* qb  = (u16*)(ws + 2 * SZ_ACT + 4 * SZ_W);
  u16* kb  = (u16*)(ws + 3 * SZ_ACT + 4 * SZ_W);
  u16* vt  = (u16*)(ws + 4 * SZ_ACT + 4 * SZ_W);
  u16* ao  = (u16*)(ws + 5 * SZ_ACT + 4 * SZ_W);

  cvt_kernel<<<dim3(8192, 2), 256, 0, stream>>>(x, y, xb, yb);
  wtrans_kernel<<<dim3(16, 16, 4), 256, 0, stream>>>(wq, wk, wv, wo, wT);
  gemm_qkv_kernel<<<dim3(512, 3), 256, 0, stream>>>(xb, yb, wqT, wkT, wvT, bq, bk, bv, qb, kb, vt);
  attn_kernel<<<dim3(64, 16), 256, 0, stream>>>(qb, kb, vt, ao);
  gemm_o_kernel<<<dim3(8, 64), 256, 0, stream>>>(ao, woT, bo, out);
}